// Round 2
// baseline (331.914 us; speedup 1.0000x reference)
//
#include <hip/hip_runtime.h>
#include <stdint.h>

// ---------------------------------------------------------------------------
// SelfAttention: out = softmax((x Wq^T)(x Wk^T)^T / sqrt(E)) (x Wv^T)
// B=4, S=2048, E=1024. Heavy math on bf16 MFMA (fp32 accumulate).
// R2: GEMM staging via global_load_lds width=16 (m97 ladder step).
// ---------------------------------------------------------------------------

typedef __attribute__((ext_vector_type(8))) short bf16x8;   // 8 bf16 = 4 VGPRs
typedef __attribute__((ext_vector_type(4))) float f32x4;

__device__ __forceinline__ float bf2f(uint16_t u) {
    return __uint_as_float(((uint32_t)u) << 16);
}
__device__ __forceinline__ uint16_t f2bf(float f) {
    uint32_t u = __float_as_uint(f);
    uint32_t r = u + 0x7FFFu + ((u >> 16) & 1u);   // RNE
    return (uint16_t)(r >> 16);
}

// async global -> LDS, 16 bytes per lane (wave-uniform base + lane*16)
__device__ __forceinline__ void gll16(const void* g, void* l) {
    __builtin_amdgcn_global_load_lds(
        (const __attribute__((address_space(1))) uint32_t*)g,
        (__attribute__((address_space(3))) uint32_t*)l,
        16, 0, 0);
}

// ---- cast fp32 -> bf16, vectorized x4 -------------------------------------
__global__ __launch_bounds__(256) void cast_f32_bf16(const float* __restrict__ in,
                                                     uint16_t* __restrict__ out,
                                                     int n4) {
    int i = blockIdx.x * 256 + threadIdx.x;
    if (i < n4) {
        float4 v = ((const float4*)in)[i];
        ushort4 o;
        o.x = f2bf(v.x); o.y = f2bf(v.y); o.z = f2bf(v.z); o.w = f2bf(v.w);
        ((ushort4*)out)[i] = o;
    }
}

// ---- bf16 tile transpose: in[rows][cols] -> out[cols][rows], z-batched ----
__global__ __launch_bounds__(256) void transpose_bf16(const uint16_t* __restrict__ in,
                                                      uint16_t* __restrict__ out,
                                                      int rows, int cols) {
    __shared__ uint16_t tile[32][33];
    size_t bo = (size_t)blockIdx.z * rows * cols;
    in += bo; out += bo;
    int bx = blockIdx.x * 32;   // col base
    int by = blockIdx.y * 32;   // row base
    int tx = threadIdx.x, ty = threadIdx.y;   // 32 x 8
    #pragma unroll
    for (int i = ty; i < 32; i += 8)
        tile[i][tx] = in[(size_t)(by + i) * cols + bx + tx];
    __syncthreads();
    #pragma unroll
    for (int i = ty; i < 32; i += 8)
        out[(size_t)(bx + i) * rows + by + tx] = tile[tx][i];
}

// ---- row softmax over 2048 bf16 elements, in place, one block per row -----
__global__ __launch_bounds__(256) void softmax_rows(uint16_t* __restrict__ P) {
    const int n = 2048;
    uint16_t* row = P + (size_t)blockIdx.x * n;
    int tid = threadIdx.x;
    int w = tid >> 6, ln = tid & 63;
    float v[8];
    float m = -3.4e38f;
    #pragma unroll
    for (int i = 0; i < 8; i++) { v[i] = bf2f(row[tid + 256 * i]); m = fmaxf(m, v[i]); }
    #pragma unroll
    for (int o = 32; o >= 1; o >>= 1) m = fmaxf(m, __shfl_down(m, o, 64));
    __shared__ float smax[4], ssum[4];
    if (ln == 0) smax[w] = m;
    __syncthreads();
    m = fmaxf(fmaxf(smax[0], smax[1]), fmaxf(smax[2], smax[3]));
    float s = 0.f;
    #pragma unroll
    for (int i = 0; i < 8; i++) { v[i] = __expf(v[i] - m); s += v[i]; }
    #pragma unroll
    for (int o = 32; o >= 1; o >>= 1) s += __shfl_down(s, o, 64);
    if (ln == 0) ssum[w] = s;
    __syncthreads();
    s = ssum[0] + ssum[1] + ssum[2] + ssum[3];
    float inv = 1.f / s;
    #pragma unroll
    for (int i = 0; i < 8; i++) row[tid + 256 * i] = f2bf(v[i] * inv);
}

// ---- NT GEMM: C[M][N] = alpha * A[M][K] * B[N][K]^T  (bf16 in, OutT out) --
// 128x128 block tile, BK=32, 256 threads = 4 waves, each wave 64x64 via
// 4x4 grid of mfma_f32_16x16x32_bf16. Staging via global_load_lds width=16:
// LDS tiles are UNPADDED row-major [128][32] (wave-uniform base + lane*16
// constraint). Stride 64 B -> 2-way bank aliasing on ds_read_b128 (free,
// m136). z-batched via element strides.
#define BM 128
#define BN 128
#define BK 32

template <typename OutT>
__global__ __launch_bounds__(256) void gemm_nt(const uint16_t* __restrict__ A,
                                               const uint16_t* __restrict__ B,
                                               OutT* __restrict__ C,
                                               int M, int N, int K, float alpha,
                                               long sA, long sB, long sC) {
    int bz = blockIdx.z;
    A += (long)bz * sA;
    B += (long)bz * sB;
    C += (long)bz * sC;

    __shared__ uint16_t As[BM * BK];   // 8 KB
    __shared__ uint16_t Bs[BN * BK];   // 8 KB

    const int tid  = threadIdx.x;
    const int m0   = blockIdx.y * BM;
    const int n0   = blockIdx.x * BN;
    const int wave = tid >> 6;
    const int lane = tid & 63;
    const int quad = lane >> 4;
    const int l16  = lane & 15;
    const int wr   = (wave >> 1) * 64;   // wave row offset in tile
    const int wc   = (wave & 1) * 64;    // wave col offset in tile

    // staging: thread covers row sr (+64), 8 bf16 (16 B) at col sc
    const int sr = tid >> 2;            // 0..63
    const int sc = (tid & 3) * 8;       // 0,8,16,24
    const uint16_t* Ag = A + (long)(m0 + sr) * K + sc;
    const uint16_t* Bg = B + (long)(n0 + sr) * K + sc;
    const long rstep = (long)64 * K;
    uint16_t* Al0 = &As[sr * BK + sc];
    uint16_t* Al1 = &As[(sr + 64) * BK + sc];
    uint16_t* Bl0 = &Bs[sr * BK + sc];
    uint16_t* Bl1 = &Bs[(sr + 64) * BK + sc];

    f32x4 acc[4][4] = {};

    for (int k0 = 0; k0 < K; k0 += BK) {
        __syncthreads();   // all waves done reading previous tiles
        gll16(Ag,         Al0);
        gll16(Ag + rstep, Al1);
        gll16(Bg,         Bl0);
        gll16(Bg + rstep, Bl1);
        Ag += BK; Bg += BK;
        __syncthreads();   // vmcnt(0) drain + barrier: tiles landed

        const int ko = quad * 8;
        bf16x8 af[4], bfr[4];
        #pragma unroll
        for (int i = 0; i < 4; i++)
            af[i] = *(const bf16x8*)(&As[(wr + i * 16 + l16) * BK + ko]);
        #pragma unroll
        for (int j = 0; j < 4; j++)
            bfr[j] = *(const bf16x8*)(&Bs[(wc + j * 16 + l16) * BK + ko]);
        #pragma unroll
        for (int i = 0; i < 4; i++)
            #pragma unroll
            for (int j = 0; j < 4; j++)
                acc[i][j] = __builtin_amdgcn_mfma_f32_16x16x32_bf16(af[i], bfr[j], acc[i][j], 0, 0, 0);
    }

    // epilogue: C/D layout col = lane&15, row = quad*4 + reg
    #pragma unroll
    for (int i = 0; i < 4; i++) {
        #pragma unroll
        for (int j = 0; j < 4; j++) {
            #pragma unroll
            for (int r = 0; r < 4; r++) {
                int row = m0 + wr + i * 16 + quad * 4 + r;
                int col = n0 + wc + j * 16 + l16;
                float val = acc[i][j][r] * alpha;
                if constexpr (sizeof(OutT) == 2)
                    C[(long)row * N + col] = f2bf(val);
                else
                    C[(long)row * N + col] = val;
            }
        }
    }
}

// ---------------------------------------------------------------------------
extern "C" void kernel_launch(void* const* d_in, const int* in_sizes, int n_in,
                              void* d_out, int out_size, void* d_ws, size_t ws_size,
                              hipStream_t stream) {
    const float* x  = (const float*)d_in[0];
    const float* Wq = (const float*)d_in[1];
    const float* Wk = (const float*)d_in[2];
    const float* Wv = (const float*)d_in[3];
    float* out = (float*)d_out;

    const int Bn = 4, S = 2048, E = 1024;
    const long MS = (long)Bn * S;              // 8192 total rows

    // workspace layout (bf16 buffers), ~118 MB total
    char* ws = (char*)d_ws;
    const size_t SZ_XB = (size_t)MS * E * 2;            // 16 MB
    const size_t SZ_W  = (size_t)E * E * 2;             //  2 MB
    const size_t SZ_P  = (size_t)Bn * S * S * 2;        // 32 MB
    const size_t SZ_VT = (size_t)Bn * E * S * 2;        // 16 MB
    uint16_t* xb  = (uint16_t*)ws;              ws += SZ_XB;
    uint16_t* wqb = (uint16_t*)ws;              ws += SZ_W;
    uint16_t* wkb = (uint16_t*)ws;              ws += SZ_W;
    uint16_t* wvb = (uint16_t*)ws;              ws += SZ_W;
    uint16_t* Qb  = (uint16_t*)ws;              ws += SZ_XB;
    uint16_t* Kb  = (uint16_t*)ws;              ws += SZ_XB;
    uint16_t* Vb  = (uint16_t*)ws;              ws += SZ_XB;
    uint16_t* Pb  = (uint16_t*)ws;              ws += SZ_P;
    uint16_t* Vt  = (uint16_t*)ws;              ws += SZ_VT;

    dim3 blk(256);

    // 1) casts to bf16
    {
        int n4 = (int)(MS * E / 4);
        cast_f32_bf16<<<dim3((n4 + 255) / 256), blk, 0, stream>>>(x, xb, n4);
        int n4w = E * E / 4;
        dim3 gw((n4w + 255) / 256);
        cast_f32_bf16<<<gw, blk, 0, stream>>>(Wq, wqb, n4w);
        cast_f32_bf16<<<gw, blk, 0, stream>>>(Wk, wkb, n4w);
        cast_f32_bf16<<<gw, blk, 0, stream>>>(Wv, wvb, n4w);
    }

    // 2) Q/K/V = xb * W^T   (M=8192, N=1024, K=1024), bf16 out
    {
        dim3 g(E / BN, MS / BM, 1);   // (8, 64)
        gemm_nt<uint16_t><<<g, blk, 0, stream>>>(xb, wqb, Qb, (int)MS, E, E, 1.f, 0, 0, 0);
        gemm_nt<uint16_t><<<g, blk, 0, stream>>>(xb, wkb, Kb, (int)MS, E, E, 1.f, 0, 0, 0);
        gemm_nt<uint16_t><<<g, blk, 0, stream>>>(xb, wvb, Vb, (int)MS, E, E, 1.f, 0, 0, 0);
    }

    // 3) Vt[b][e][k] = V[b][k][e]
    transpose_bf16<<<dim3(E / 32, S / 32, Bn), dim3(32, 8), 0, stream>>>(Vb, Vt, S, E);

    // 4) scores = (Q K^T) / sqrt(E)  per batch, bf16 out
    {
        dim3 g(S / BN, S / BM, Bn);   // (16, 16, 4)
        gemm_nt<uint16_t><<<g, blk, 0, stream>>>(Qb, Kb, Pb, S, S, E, 0.03125f,
                                                 (long)S * E, (long)S * E, (long)S * S);
    }

    // 5) softmax rows in place (4*2048 rows of 2048)
    softmax_rows<<<dim3(Bn * S), blk, 0, stream>>>(Pb);

    // 6) out = P * V = P * Vt^T  (M=2048, N=1024, K=2048 per batch), fp32 out
    {
        dim3 g(E / BN, S / BM, Bn);   // (8, 16, 4)
        gemm_nt<float><<<g, blk, 0, stream>>>(Pb, Vt, out, S, E, S, 1.f,
                                              (long)S * S, (long)E * S, (long)S * E);
    }
}

// Round 3
// 312.101 us; speedup vs baseline: 1.0635x; 1.0635x over previous
//
#include <hip/hip_runtime.h>
#include <stdint.h>

// ---------------------------------------------------------------------------
// SelfAttention: out = softmax((x Wq^T)(x Wk^T)^T / sqrt(E)) (x Wv^T)
// B=4, S=2048, E=1024. Heavy math on bf16 MFMA (fp32 accumulate).
// R3: double-buffered LDS with prefetch distance 1 — hides the per-iteration
// global->LDS latency that R1/R2 exposed (MfmaUtil 20%, nothing busy).
// ---------------------------------------------------------------------------

typedef __attribute__((ext_vector_type(8))) short bf16x8;   // 8 bf16 = 4 VGPRs
typedef __attribute__((ext_vector_type(4))) float f32x4;

__device__ __forceinline__ float bf2f(uint16_t u) {
    return __uint_as_float(((uint32_t)u) << 16);
}
__device__ __forceinline__ uint16_t f2bf(float f) {
    uint32_t u = __float_as_uint(f);
    uint32_t r = u + 0x7FFFu + ((u >> 16) & 1u);   // RNE
    return (uint16_t)(r >> 16);
}

// async global -> LDS, 16 bytes per lane (wave-uniform base + lane*16)
__device__ __forceinline__ void gll16(const void* g, void* l) {
    __builtin_amdgcn_global_load_lds(
        (const __attribute__((address_space(1))) uint32_t*)g,
        (__attribute__((address_space(3))) uint32_t*)l,
        16, 0, 0);
}

// ---- cast fp32 -> bf16, vectorized x4 -------------------------------------
__global__ __launch_bounds__(256) void cast_f32_bf16(const float* __restrict__ in,
                                                     uint16_t* __restrict__ out,
                                                     int n4) {
    int i = blockIdx.x * 256 + threadIdx.x;
    if (i < n4) {
        float4 v = ((const float4*)in)[i];
        ushort4 o;
        o.x = f2bf(v.x); o.y = f2bf(v.y); o.z = f2bf(v.z); o.w = f2bf(v.w);
        ((ushort4*)out)[i] = o;
    }
}

// ---- bf16 tile transpose: in[rows][cols] -> out[cols][rows], z-batched ----
__global__ __launch_bounds__(256) void transpose_bf16(const uint16_t* __restrict__ in,
                                                      uint16_t* __restrict__ out,
                                                      int rows, int cols) {
    __shared__ uint16_t tile[32][33];
    size_t bo = (size_t)blockIdx.z * rows * cols;
    in += bo; out += bo;
    int bx = blockIdx.x * 32;   // col base
    int by = blockIdx.y * 32;   // row base
    int tx = threadIdx.x, ty = threadIdx.y;   // 32 x 8
    #pragma unroll
    for (int i = ty; i < 32; i += 8)
        tile[i][tx] = in[(size_t)(by + i) * cols + bx + tx];
    __syncthreads();
    #pragma unroll
    for (int i = ty; i < 32; i += 8)
        out[(size_t)(bx + i) * rows + by + tx] = tile[tx][i];
}

// ---- row softmax over 2048 bf16 elements, in place, one block per row -----
__global__ __launch_bounds__(256) void softmax_rows(uint16_t* __restrict__ P) {
    const int n = 2048;
    uint16_t* row = P + (size_t)blockIdx.x * n;
    int tid = threadIdx.x;
    int w = tid >> 6, ln = tid & 63;
    float v[8];
    float m = -3.4e38f;
    #pragma unroll
    for (int i = 0; i < 8; i++) { v[i] = bf2f(row[tid + 256 * i]); m = fmaxf(m, v[i]); }
    #pragma unroll
    for (int o = 32; o >= 1; o >>= 1) m = fmaxf(m, __shfl_down(m, o, 64));
    __shared__ float smax[4], ssum[4];
    if (ln == 0) smax[w] = m;
    __syncthreads();
    m = fmaxf(fmaxf(smax[0], smax[1]), fmaxf(smax[2], smax[3]));
    float s = 0.f;
    #pragma unroll
    for (int i = 0; i < 8; i++) { v[i] = __expf(v[i] - m); s += v[i]; }
    #pragma unroll
    for (int o = 32; o >= 1; o >>= 1) s += __shfl_down(s, o, 64);
    if (ln == 0) ssum[w] = s;
    __syncthreads();
    s = ssum[0] + ssum[1] + ssum[2] + ssum[3];
    float inv = 1.f / s;
    #pragma unroll
    for (int i = 0; i < 8; i++) row[tid + 256 * i] = f2bf(v[i] * inv);
}

// ---- NT GEMM: C[M][N] = alpha * A[M][K] * B[N][K]^T  (bf16 in, OutT out) --
// 128x128 block tile, BK=32, 256 threads = 4 waves, each wave 64x64 via
// 4x4 grid of mfma_f32_16x16x32_bf16. Staging via global_load_lds width=16
// into DOUBLE-BUFFERED unpadded LDS tiles [2][128][32]: loads for tile k+1
// are issued right after the barrier, so the vmcnt(0) drain at the NEXT
// barrier happens a full compute phase after issue (latency hidden).
// z-batched via element strides.
#define BM 128
#define BN 128
#define BK 32

template <typename OutT>
__global__ __launch_bounds__(256) void gemm_nt(const uint16_t* __restrict__ A,
                                               const uint16_t* __restrict__ B,
                                               OutT* __restrict__ C,
                                               int M, int N, int K, float alpha,
                                               long sA, long sB, long sC) {
    int bz = blockIdx.z;
    A += (long)bz * sA;
    B += (long)bz * sB;
    C += (long)bz * sC;

    __shared__ uint16_t As[2][BM * BK];   // 2 x 8 KB
    __shared__ uint16_t Bs[2][BN * BK];   // 2 x 8 KB

    const int tid  = threadIdx.x;
    const int m0   = blockIdx.y * BM;
    const int n0   = blockIdx.x * BN;
    const int wave = tid >> 6;
    const int lane = tid & 63;
    const int quad = lane >> 4;
    const int l16  = lane & 15;
    const int wr   = (wave >> 1) * 64;   // wave row offset in tile
    const int wc   = (wave & 1) * 64;    // wave col offset in tile

    // staging: thread covers row sr (+64), 8 bf16 (16 B) at col sc
    const int sr = tid >> 2;            // 0..63
    const int sc = (tid & 3) * 8;       // 0,8,16,24
    const uint16_t* Ag = A + (long)(m0 + sr) * K + sc;
    const uint16_t* Bg = B + (long)(n0 + sr) * K + sc;
    const long rstep = (long)64 * K;
    const int so0 = sr * BK + sc;
    const int so1 = (sr + 64) * BK + sc;

    // prologue: prefetch tile 0 into buffer 0
    gll16(Ag,         &As[0][so0]);
    gll16(Ag + rstep, &As[0][so1]);
    gll16(Bg,         &Bs[0][so0]);
    gll16(Bg + rstep, &Bs[0][so1]);
    Ag += BK; Bg += BK;

    f32x4 acc[4][4] = {};
    const int nk = K / BK;

    for (int k = 0; k < nk; ++k) {
        const int cur = k & 1;
        __syncthreads();   // drains vmcnt(0): buffer `cur` is resident;
                           // also: all waves done reading buffer cur^1
        if (k + 1 < nk) {
            const int nxt = cur ^ 1;
            gll16(Ag,         &As[nxt][so0]);
            gll16(Ag + rstep, &As[nxt][so1]);
            gll16(Bg,         &Bs[nxt][so0]);
            gll16(Bg + rstep, &Bs[nxt][so1]);
            Ag += BK; Bg += BK;
        }

        const int ko = quad * 8;
        bf16x8 af[4], bfr[4];
        #pragma unroll
        for (int i = 0; i < 4; i++)
            af[i] = *(const bf16x8*)(&As[cur][(wr + i * 16 + l16) * BK + ko]);
        #pragma unroll
        for (int j = 0; j < 4; j++)
            bfr[j] = *(const bf16x8*)(&Bs[cur][(wc + j * 16 + l16) * BK + ko]);
        #pragma unroll
        for (int i = 0; i < 4; i++)
            #pragma unroll
            for (int j = 0; j < 4; j++)
                acc[i][j] = __builtin_amdgcn_mfma_f32_16x16x32_bf16(af[i], bfr[j], acc[i][j], 0, 0, 0);
    }

    // epilogue: C/D layout col = lane&15, row = quad*4 + reg
    #pragma unroll
    for (int i = 0; i < 4; i++) {
        #pragma unroll
        for (int j = 0; j < 4; j++) {
            #pragma unroll
            for (int r = 0; r < 4; r++) {
                int row = m0 + wr + i * 16 + quad * 4 + r;
                int col = n0 + wc + j * 16 + l16;
                float val = acc[i][j][r] * alpha;
                if constexpr (sizeof(OutT) == 2)
                    C[(long)row * N + col] = f2bf(val);
                else
                    C[(long)row * N + col] = val;
            }
        }
    }
}

// ---------------------------------------------------------------------------
extern "C" void kernel_launch(void* const* d_in, const int* in_sizes, int n_in,
                              void* d_out, int out_size, void* d_ws, size_t ws_size,
                              hipStream_t stream) {
    const float* x  = (const float*)d_in[0];
    const float* Wq = (const float*)d_in[1];
    const float* Wk = (const float*)d_in[2];
    const float* Wv = (const float*)d_in[3];
    float* out = (float*)d_out;

    const int Bn = 4, S = 2048, E = 1024;
    const long MS = (long)Bn * S;              // 8192 total rows

    // workspace layout (bf16 buffers), ~118 MB total
    char* ws = (char*)d_ws;
    const size_t SZ_XB = (size_t)MS * E * 2;            // 16 MB
    const size_t SZ_W  = (size_t)E * E * 2;             //  2 MB
    const size_t SZ_P  = (size_t)Bn * S * S * 2;        // 32 MB
    const size_t SZ_VT = (size_t)Bn * E * S * 2;        // 16 MB
    uint16_t* xb  = (uint16_t*)ws;              ws += SZ_XB;
    uint16_t* wqb = (uint16_t*)ws;              ws += SZ_W;
    uint16_t* wkb = (uint16_t*)ws;              ws += SZ_W;
    uint16_t* wvb = (uint16_t*)ws;              ws += SZ_W;
    uint16_t* Qb  = (uint16_t*)ws;              ws += SZ_XB;
    uint16_t* Kb  = (uint16_t*)ws;              ws += SZ_XB;
    uint16_t* Vb  = (uint16_t*)ws;              ws += SZ_XB;
    uint16_t* Pb  = (uint16_t*)ws;              ws += SZ_P;
    uint16_t* Vt  = (uint16_t*)ws;              ws += SZ_VT;

    dim3 blk(256);

    // 1) casts to bf16
    {
        int n4 = (int)(MS * E / 4);
        cast_f32_bf16<<<dim3((n4 + 255) / 256), blk, 0, stream>>>(x, xb, n4);
        int n4w = E * E / 4;
        dim3 gw((n4w + 255) / 256);
        cast_f32_bf16<<<gw, blk, 0, stream>>>(Wq, wqb, n4w);
        cast_f32_bf16<<<gw, blk, 0, stream>>>(Wk, wkb, n4w);
        cast_f32_bf16<<<gw, blk, 0, stream>>>(Wv, wvb, n4w);
    }

    // 2) Q/K/V = xb * W^T   (M=8192, N=1024, K=1024), bf16 out
    {
        dim3 g(E / BN, MS / BM, 1);   // (8, 64)
        gemm_nt<uint16_t><<<g, blk, 0, stream>>>(xb, wqb, Qb, (int)MS, E, E, 1.f, 0, 0, 0);
        gemm_nt<uint16_t><<<g, blk, 0, stream>>>(xb, wkb, Kb, (int)MS, E, E, 1.f, 0, 0, 0);
        gemm_nt<uint16_t><<<g, blk, 0, stream>>>(xb, wvb, Vb, (int)MS, E, E, 1.f, 0, 0, 0);
    }

    // 3) Vt[b][e][k] = V[b][k][e]
    transpose_bf16<<<dim3(E / 32, S / 32, Bn), dim3(32, 8), 0, stream>>>(Vb, Vt, S, E);

    // 4) scores = (Q K^T) / sqrt(E)  per batch, bf16 out
    {
        dim3 g(S / BN, S / BM, Bn);   // (16, 16, 4)
        gemm_nt<uint16_t><<<g, blk, 0, stream>>>(Qb, Kb, Pb, S, S, E, 0.03125f,
                                                 (long)S * E, (long)S * E, (long)S * S);
    }

    // 5) softmax rows in place (4*2048 rows of 2048)
    softmax_rows<<<dim3(Bn * S), blk, 0, stream>>>(Pb);

    // 6) out = P * V = P * Vt^T  (M=2048, N=1024, K=2048 per batch), fp32 out
    {
        dim3 g(E / BN, S / BM, Bn);   // (8, 16, 4)
        gemm_nt<float><<<g, blk, 0, stream>>>(Pb, Vt, out, S, E, S, 1.f,
                                              (long)S * S, (long)E * S, (long)S * E);
    }
}

// Round 4
// 278.561 us; speedup vs baseline: 1.1915x; 1.1204x over previous
//
#include <hip/hip_runtime.h>
#include <stdint.h>

// ---------------------------------------------------------------------------
// SelfAttention: out = softmax((x Wq^T)(x Wk^T)^T / sqrt(E)) (x Wv^T)
// B=4, S=2048, E=1024. bf16 MFMA, fp32 accumulate.
// R4: (1) 3-stage LDS ring with raw s_waitcnt vmcnt(4)+s_barrier (depth-2
//     prefetch past the barrier), (2) XCD-contiguous block swizzle with 8x8
//     supertiles for L2 locality, (3) fused QKV GEMM (N=3072, shared A).
// ---------------------------------------------------------------------------

typedef __attribute__((ext_vector_type(8))) short bf16x8;   // 8 bf16 = 4 VGPRs
typedef __attribute__((ext_vector_type(4))) float f32x4;

__device__ __forceinline__ float bf2f(uint16_t u) {
    return __uint_as_float(((uint32_t)u) << 16);
}
__device__ __forceinline__ uint16_t f2bf(float f) {
    uint32_t u = __float_as_uint(f);
    uint32_t r = u + 0x7FFFu + ((u >> 16) & 1u);   // RNE
    return (uint16_t)(r >> 16);
}

// async global -> LDS, 16 bytes per lane (wave-uniform base + lane*16)
__device__ __forceinline__ void gll16(const void* g, void* l) {
    __builtin_amdgcn_global_load_lds(
        (const __attribute__((address_space(1))) uint32_t*)g,
        (__attribute__((address_space(3))) uint32_t*)l,
        16, 0, 0);
}

// ---- cast fp32 -> bf16, vectorized x4 -------------------------------------
__global__ __launch_bounds__(256) void cast_f32_bf16(const float* __restrict__ in,
                                                     uint16_t* __restrict__ out,
                                                     int n4) {
    int i = blockIdx.x * 256 + threadIdx.x;
    if (i < n4) {
        float4 v = ((const float4*)in)[i];
        ushort4 o;
        o.x = f2bf(v.x); o.y = f2bf(v.y); o.z = f2bf(v.z); o.w = f2bf(v.w);
        ((ushort4*)out)[i] = o;
    }
}

// ---- bf16 strided transpose: in[r][c] (stride istride) -> out[c][r] -------
__global__ __launch_bounds__(256) void transpose_bf16(const uint16_t* __restrict__ in,
                                                      uint16_t* __restrict__ out,
                                                      int rows, int cols, int istride,
                                                      long ibatch, long obatch) {
    __shared__ uint16_t tile[32][33];
    in  += (long)blockIdx.z * ibatch;
    out += (long)blockIdx.z * obatch;
    int bx = blockIdx.x * 32;   // col base
    int by = blockIdx.y * 32;   // row base
    int tx = threadIdx.x, ty = threadIdx.y;   // 32 x 8
    #pragma unroll
    for (int i = ty; i < 32; i += 8)
        tile[i][tx] = in[(long)(by + i) * istride + bx + tx];
    __syncthreads();
    #pragma unroll
    for (int i = ty; i < 32; i += 8)
        out[(long)(bx + i) * rows + by + tx] = tile[tx][i];
}

// ---- row softmax over 2048 bf16 elements, in place, one block per row -----
__global__ __launch_bounds__(256) void softmax_rows(uint16_t* __restrict__ P) {
    const int n = 2048;
    uint16_t* row = P + (size_t)blockIdx.x * n;
    int tid = threadIdx.x;
    int w = tid >> 6, ln = tid & 63;
    float v[8];
    float m = -3.4e38f;
    #pragma unroll
    for (int i = 0; i < 8; i++) { v[i] = bf2f(row[tid + 256 * i]); m = fmaxf(m, v[i]); }
    #pragma unroll
    for (int o = 32; o >= 1; o >>= 1) m = fmaxf(m, __shfl_down(m, o, 64));
    __shared__ float smax[4], ssum[4];
    if (ln == 0) smax[w] = m;
    __syncthreads();
    m = fmaxf(fmaxf(smax[0], smax[1]), fmaxf(smax[2], smax[3]));
    float s = 0.f;
    #pragma unroll
    for (int i = 0; i < 8; i++) { v[i] = __expf(v[i] - m); s += v[i]; }
    #pragma unroll
    for (int o = 32; o >= 1; o >>= 1) s += __shfl_down(s, o, 64);
    if (ln == 0) ssum[w] = s;
    __syncthreads();
    s = ssum[0] + ssum[1] + ssum[2] + ssum[3];
    float inv = 1.f / s;
    #pragma unroll
    for (int i = 0; i < 8; i++) row[tid + 256 * i] = f2bf(v[i] * inv);
}

// ---- NT GEMM: C[M][N] = alpha * A[M][K] * B[N][K]^T  (bf16 in, OutT out) --
// 128x128 tile, BK=32, 4 waves, 4x4 mfma_f32_16x16x32_bf16 per wave.
// 3-stage LDS ring, global_load_lds width=16, raw vmcnt(4)+barrier so the
// newest stage's loads stay in flight across the barrier (depth-2 prefetch).
// 1D grid with XCD-contiguous swizzle + 8x8 supertile decode.
// gx = N/BN, gy = M/BM must be multiples of 8 (all call sites satisfy this).
#define BM 128
#define BN 128
#define BK 32

template <typename OutT>
__global__ __launch_bounds__(256) void gemm_nt(const uint16_t* __restrict__ A,
                                               const uint16_t* __restrict__ B,
                                               OutT* __restrict__ C,
                                               int gx, int gy,
                                               long lda, long ldb, long ldc,
                                               int K, float alpha,
                                               long sA, long sB, long sC) {
    // ---- XCD-contiguous swizzle + 8x8 supertile decode ----
    const int total = gridDim.x;
    const int n     = blockIdx.x;
    const int per   = total >> 3;
    const int g     = (n & 7) * per + (n >> 3);    // contiguous range per XCD
    const int pb    = gx * gy;                     // blocks per batch (z)
    const int bz    = g / pb;
    const int r     = g - bz * pb;
    const int stpr  = gx >> 3;                     // supertiles per row-band
    const int st    = r >> 6;
    const int w     = r & 63;
    const int sty   = st / stpr;
    const int stx   = st - sty * stpr;
    const int bx    = (stx << 3) + (w & 7);
    const int by    = (sty << 3) + (w >> 3);

    A += (long)bz * sA;
    B += (long)bz * sB;
    C += (long)bz * sC;

    __shared__ uint16_t As[3][BM * BK];   // 3 x 8 KB
    __shared__ uint16_t Bs[3][BM * BK];   // 3 x 8 KB

    const int tid  = threadIdx.x;
    const int m0   = by * BM;
    const int n0   = bx * BN;
    const int wave = tid >> 6;
    const int lane = tid & 63;
    const int quad = lane >> 4;
    const int l16  = lane & 15;
    const int wr   = (wave >> 1) * 64;   // wave row offset in tile
    const int wc   = (wave & 1) * 64;    // wave col offset in tile

    // staging: thread covers row sr (+64), 8 bf16 (16 B) at col sc
    const int sr = tid >> 2;            // 0..63
    const int sc = (tid & 3) * 8;       // 0,8,16,24
    const uint16_t* Ag = A + (long)(m0 + sr) * lda + sc;
    const uint16_t* Bg = B + (long)(n0 + sr) * ldb + sc;
    const long rsA = 64 * lda;
    const long rsB = 64 * ldb;
    const int so0 = sr * BK + sc;
    const int so1 = (sr + 64) * BK + sc;

    const int nk = K / BK;

    // prologue: prefetch tiles 0 and 1 into slots 0 and 1 (8 loads in flight)
    gll16(Ag,       &As[0][so0]);
    gll16(Ag + rsA, &As[0][so1]);
    gll16(Bg,       &Bs[0][so0]);
    gll16(Bg + rsB, &Bs[0][so1]);
    Ag += BK; Bg += BK;
    gll16(Ag,       &As[1][so0]);
    gll16(Ag + rsA, &As[1][so1]);
    gll16(Bg,       &Bs[1][so0]);
    gll16(Bg + rsB, &Bs[1][so1]);
    Ag += BK; Bg += BK;

    f32x4 acc[4][4] = {};
    int cur = 0, pf = 2;

    for (int k = 0; k < nk; ++k) {
        // retire only the tile we are about to consume (its 4 loads are the
        // oldest); keep the newest 4 in flight across the barrier.
        if (k < nk - 1) {
            asm volatile("s_waitcnt vmcnt(4)\n\ts_barrier" ::: "memory");
        } else {
            asm volatile("s_waitcnt vmcnt(0)\n\ts_barrier" ::: "memory");
        }

        if (k + 2 < nk) {
            gll16(Ag,       &As[pf][so0]);
            gll16(Ag + rsA, &As[pf][so1]);
            gll16(Bg,       &Bs[pf][so0]);
            gll16(Bg + rsB, &Bs[pf][so1]);
            Ag += BK; Bg += BK;
        }

        const uint16_t* Ac = As[cur];
        const uint16_t* Bc = Bs[cur];
        const int ko = quad * 8;
        bf16x8 af[4], bfr[4];
        #pragma unroll
        for (int i = 0; i < 4; i++)
            af[i] = *(const bf16x8*)(&Ac[(wr + i * 16 + l16) * BK + ko]);
        #pragma unroll
        for (int j = 0; j < 4; j++)
            bfr[j] = *(const bf16x8*)(&Bc[(wc + j * 16 + l16) * BK + ko]);
        #pragma unroll
        for (int i = 0; i < 4; i++)
            #pragma unroll
            for (int j = 0; j < 4; j++)
                acc[i][j] = __builtin_amdgcn_mfma_f32_16x16x32_bf16(af[i], bfr[j], acc[i][j], 0, 0, 0);

        cur = (cur == 2) ? 0 : cur + 1;
        pf  = (pf  == 2) ? 0 : pf + 1;
    }

    // epilogue: C/D layout col = lane&15, row = quad*4 + reg
    #pragma unroll
    for (int i = 0; i < 4; i++) {
        #pragma unroll
        for (int j = 0; j < 4; j++) {
            #pragma unroll
            for (int r4 = 0; r4 < 4; r4++) {
                int row = m0 + wr + i * 16 + quad * 4 + r4;
                int col = n0 + wc + j * 16 + l16;
                float val = acc[i][j][r4] * alpha;
                if constexpr (sizeof(OutT) == 2)
                    C[(long)row * ldc + col] = f2bf(val);
                else
                    C[(long)row * ldc + col] = val;
            }
        }
    }
}

// ---------------------------------------------------------------------------
extern "C" void kernel_launch(void* const* d_in, const int* in_sizes, int n_in,
                              void* d_out, int out_size, void* d_ws, size_t ws_size,
                              hipStream_t stream) {
    const float* x  = (const float*)d_in[0];
    const float* Wq = (const float*)d_in[1];
    const float* Wk = (const float*)d_in[2];
    const float* Wv = (const float*)d_in[3];
    float* out = (float*)d_out;

    const int Bn = 4, S = 2048, E = 1024;
    const long MS = (long)Bn * S;              // 8192 total rows
    const int  N3 = 3 * E;                     // 3072

    // workspace layout (bf16), 118 MB total
    char* ws = (char*)d_ws;
    uint16_t* xb    = (uint16_t*)ws;  ws += (size_t)MS * E * 2;        // 16 MB
    uint16_t* wqkvb = (uint16_t*)ws;  ws += (size_t)N3 * E * 2;        //  6 MB
    uint16_t* QKVb  = (uint16_t*)ws;  ws += (size_t)MS * N3 * 2;       // 48 MB
    uint16_t* Pb    = (uint16_t*)ws;  ws += (size_t)Bn * S * S * 2;    // 32 MB
    uint16_t* Vt    = (uint16_t*)ws;  ws += (size_t)Bn * E * S * 2;    // 16 MB

    dim3 blk(256);

    // 1) casts to bf16 (W stacked [Wq;Wk;Wv] -> [3072][1024])
    {
        int n4 = (int)(MS * E / 4);
        cast_f32_bf16<<<dim3((n4 + 255) / 256), blk, 0, stream>>>(x, xb, n4);
        int n4w = E * E / 4;
        dim3 gw((n4w + 255) / 256);
        cast_f32_bf16<<<gw, blk, 0, stream>>>(Wq, wqkvb,             n4w);
        cast_f32_bf16<<<gw, blk, 0, stream>>>(Wk, wqkvb + (size_t)E * E,     n4w);
        cast_f32_bf16<<<gw, blk, 0, stream>>>(Wv, wqkvb + (size_t)2 * E * E, n4w);
    }

    // 2) fused QKV: QKVb[M][3072] = xb[M][1024] * wqkvb[3072][1024]^T
    {
        int gx = N3 / BN, gy = (int)(MS / BM);   // 24 x 64
        gemm_nt<uint16_t><<<dim3(gx * gy), blk, 0, stream>>>(
            xb, wqkvb, QKVb, gx, gy, E, E, N3, E, 1.f, 0, 0, 0);
    }

    // 3) Vt[b][e][s] = V[b][s][e]  (V = QKVb cols [2048,3072))
    transpose_bf16<<<dim3(E / 32, S / 32, Bn), dim3(32, 8), 0, stream>>>(
        QKVb + 2 * E, Vt, S, E, N3, (long)S * N3, (long)E * S);

    // 4) scores = (Q K^T) / sqrt(E) per batch, bf16 out
    {
        int gx = S / BN, gy = S / BM;            // 16 x 16, z=4
        gemm_nt<uint16_t><<<dim3(gx * gy * Bn), blk, 0, stream>>>(
            QKVb, QKVb + E, Pb, gx, gy, N3, N3, S, E, 0.03125f,
            (long)S * N3, (long)S * N3, (long)S * S);
    }

    // 5) softmax rows in place (4*2048 rows of 2048)
    softmax_rows<<<dim3(Bn * S), blk, 0, stream>>>(Pb);

    // 6) out = P * Vt^T  (M=2048, N=1024, K=2048 per batch), fp32 out
    {
        int gx = E / BN, gy = S / BM;            // 8 x 16, z=4
        gemm_nt<float><<<dim3(gx * gy * Bn), blk, 0, stream>>>(
            Pb, Vt, out, gx, gy, S, S, E, S, 1.f,
            (long)S * S, (long)E * S, (long)S * E);
    }
}